// Round 5
// baseline (964.272 us; speedup 1.0000x reference)
//
#include <hip/hip_runtime.h>
#include <hip/hip_bf16.h>

#define DEVI __device__ __forceinline__

typedef __bf16 bf16x8 __attribute__((ext_vector_type(8)));
typedef float f32x4 __attribute__((ext_vector_type(4)));

namespace {

constexpr int H = 2048;
constexpr int INTER = 8192;
constexpr int M_MOD = 2;
constexpr int N_TOK = 8192;
constexpr int G = N_TOK / M_MOD;   // 4096 tokens per modality
constexpr int UP_OUT = 2 * INTER;  // 16384

DEVI unsigned short f2bf(float f) {
  unsigned u = __builtin_bit_cast(unsigned, f);
  u += 0x7fffu + ((u >> 16) & 1u);  // round-to-nearest-even
  return (unsigned short)(u >> 16);
}

DEVI void gload_lds16(const void* g, void* lds) {
  __builtin_amdgcn_global_load_lds(
      (const __attribute__((address_space(1))) unsigned int*)g,
      (__attribute__((address_space(3))) unsigned int*)lds, 16, 0, 0);
}

DEVI void memfence_barrier() {
  asm volatile("" ::: "memory");
  __builtin_amdgcn_s_barrier();
  asm volatile("" ::: "memory");
}

__global__ __launch_bounds__(256) void cvt_f32_bf16(
    const float* __restrict__ in, unsigned short* __restrict__ out, int n4) {
  int idx = blockIdx.x * blockDim.x + threadIdx.x;
  int stride = gridDim.x * blockDim.x;
  for (int i = idx; i < n4; i += stride) {
    float4 v = ((const float4*)in)[i];
    ushort4 o;
    o.x = f2bf(v.x); o.y = f2bf(v.y); o.z = f2bf(v.z); o.w = f2bf(v.w);
    ((ushort4*)out)[i] = o;
  }
}

__global__ __launch_bounds__(256) void rmsnorm_kernel(
    const float* __restrict__ x, const float* __restrict__ w_norm,
    unsigned short* __restrict__ tm) {
  const int row = blockIdx.x;
  const int mod = row >> 12;  // 4096 rows per modality
  const int t = threadIdx.x;
  const float4* xr = (const float4*)(x + (size_t)row * H);
  const float4* wr = (const float4*)(w_norm + (size_t)mod * H);

  float4 v0 = xr[t];
  float4 v1 = xr[t + 256];
  float ss = v0.x * v0.x + v0.y * v0.y + v0.z * v0.z + v0.w * v0.w +
             v1.x * v1.x + v1.y * v1.y + v1.z * v1.z + v1.w * v1.w;
  #pragma unroll
  for (int o = 32; o > 0; o >>= 1) ss += __shfl_down(ss, o);
  __shared__ float red[4];
  const int w = t >> 6, l = t & 63;
  if (l == 0) red[w] = ss;
  __syncthreads();
  float tot = red[0] + red[1] + red[2] + red[3];
  float rn = rsqrtf(tot * (1.0f / H) + 1e-6f);

  float4 w0 = wr[t];
  float4 w1 = wr[t + 256];
  ushort4 o0, o1;
  o0.x = f2bf(v0.x * rn * (1.f + w0.x));
  o0.y = f2bf(v0.y * rn * (1.f + w0.y));
  o0.z = f2bf(v0.z * rn * (1.f + w0.z));
  o0.w = f2bf(v0.w * rn * (1.f + w0.w));
  o1.x = f2bf(v1.x * rn * (1.f + w1.x));
  o1.y = f2bf(v1.y * rn * (1.f + w1.y));
  o1.z = f2bf(v1.z * rn * (1.f + w1.z));
  o1.w = f2bf(v1.w * rn * (1.f + w1.w));
  ushort4* tr = (ushort4*)(tm + (size_t)row * H);
  tr[t] = o0;
  tr[t + 256] = o1;
}

// ---------------------------------------------------------------------------
// 256x256-tile 8-phase NT GEMM (T1+T2+T3+T4+T5 stack, m201-style).
// C[r,c] = sum_k A[r,k]*B[c,k]; A/B bf16 row-major, K contiguous. BK=64.
// 8 waves (2Mx4N), 512 thr. LDS 128KB: smem[dbuf][A/B][256x64 bf16].
//
// R4 DEEP-PREFETCH schedule: stages re-mapped to earliest WAR-safe slots so
// every half-tile has >=4 phases (~2500 cyc) in flight before its vmcnt —
// beats the ~900-cyc HBM-miss latency (R4 had only ~1 phase for the last
// half-tile, costing ~20% MfmaUtil in vmcnt stalls).
//   Read-retire facts: all B-reads of a buf retire by phase-1(/5)-end
//   barrier; all A-reads by phase-2(/6)-end barrier. Hence:
//     phase 2: stage h+10,h+11 (buf0-B, tile 2i+2)   [B free after p1]
//     phase 3: stage h+8,h+9   (buf0-A, tile 2i+2);  vmcnt(8) = tile 2i+1
//     phase 6: stage h+14,h+15 (buf1-B, tile 2i+3)
//     phase 7: stage h+12,h+13 (buf1-A, tile 2i+3);  vmcnt(8) = tile 2i+2
//   Ledger (2 ops/stage, in-order retire): prologue h0..h3,h6,h7,h4,h5 +
//   vmcnt(8) -> tile0 ready, {h4..h7} in flight. At p3: 16 outstanding,
//   vmcnt(8) retires oldest 8 = {h6,h7,h4,h5} = tile 2i+1 exactly.
// TAIL: out-of-range stages WRAP (h -= HMAX); HMAX % 8 == 0 so regions and
// ledger are identical to steady state; wrapped data never read.
// XOR swizzle: linear gload_lds dest, pre-swizzled global source chunk,
// XOR'd ds_read (verified 0-conflict in R2/R4).
// EPI==0: fused swiglu7 -> bf16 (INTER ld). EPI==1: fp32 out (H ld).
// ---------------------------------------------------------------------------
template <int K, int CT_PER_MOD, int EPI>
__global__ __launch_bounds__(512, 2) void gemm8p(
    const unsigned short* __restrict__ A0, const unsigned short* __restrict__ B0,
    void* __restrict__ O0, long sAm, long sBm, long sOm) {
  __shared__ __align__(16) char smem[2][2][32768];

  constexpr int NT = K / 64;     // K-tiles (even for both instantiations)
  constexpr int HMAX = 4 * NT;   // half-tiles total (HMAX % 8 == 0)
  constexpr int NITER = NT / 2;
  constexpr int PER_MOD = 16 * CT_PER_MOD;  // 4096/256 = 16 row tiles
  constexpr int NWG = 2 * PER_MOD;
  constexpr int CPX = NWG / 8;

  // T1: bijective XCD swizzle (NWG % 8 == 0 for both instantiations)
  const int bid0 = blockIdx.x;
  const int bid = (bid0 % 8) * CPX + bid0 / 8;
  const int mod = bid / PER_MOD;
  const int q = bid % PER_MOD;
  const int ct = q / 16;  // col tile; rt inner so consecutive share B-panel
  const int rt = q % 16;

  const unsigned short* A = A0 + (long)mod * sAm;
  const unsigned short* B = B0 + (long)mod * sBm;

  const int t = threadIdx.x;
  const int w = t >> 6;
  const int l = t & 63;
  const int wr = w >> 2;  // 0..1
  const int wc = w & 3;   // 0..3

  const int fr = l & 15;
  const int fk = l >> 4;
  const int frx = (fr & 7) << 4;

  // ---- staging (per thread: 2 x gload_lds per half-tile)
  const unsigned short* gArow = A + (size_t)rt * 256 * K;
  const unsigned short* gBrow = B + (size_t)ct * 256 * K;
  const int srow = t >> 3;                        // 0..63
  const int scol = ((t & 7) ^ (srow & 7)) * 8;    // swizzled chunk (elements)

  auto stage = [&](int h) {
    if (h >= HMAX) h -= HMAX;  // tail wrap: same regions, exact vmcnt ledger
    const int tt = h >> 2, qq = h & 3;
    const int isB = qq >> 1, half = qq & 1, buf = tt & 1;
    const unsigned short* src = (isB ? gBrow : gArow) +
        (size_t)(half * 128 + srow) * K + tt * 64 + scol;
    char* dst = smem[buf][isB] + half * 16384 + t * 16;
    gload_lds16(src, dst);
    gload_lds16(src + (size_t)64 * K, dst + 8192);
  };

  // ---- LDS fragment reads (swizzled)
  auto rdA = [&](const char* base, int mi, int ks) -> bf16x8 {
    const int row = wr * 128 + mi * 16 + fr;
    return *(const bf16x8*)(base + row * 128 + ((((ks << 2) + fk) << 4) ^ frx));
  };
  auto rdB = [&](const char* base, int ni, int ks) -> bf16x8 {
    const int row = wc * 64 + ni * 16 + fr;
    return *(const bf16x8*)(base + row * 128 + ((((ks << 2) + fk) << 4) ^ frx));
  };

  f32x4 acc[8][4];
  #pragma unroll
  for (int m = 0; m < 8; ++m)
    #pragma unroll
    for (int n = 0; n < 4; ++n) acc[m][n] = (f32x4){0.f, 0.f, 0.f, 0.f};

  bf16x8 a[4][2], b[4][2];

#define MFMAQ(MLO, NLO)                                                       \
  __builtin_amdgcn_s_setprio(1);                                              \
  _Pragma("unroll") for (int ks = 0; ks < 2; ++ks)                            \
  _Pragma("unroll") for (int mi = 0; mi < 4; ++mi)                            \
  _Pragma("unroll") for (int ni = 0; ni < 2; ++ni)                            \
    acc[(MLO) + mi][(NLO) + ni] = __builtin_amdgcn_mfma_f32_16x16x32_bf16(    \
        a[mi][ks], b[(NLO) + ni][ks], acc[(MLO) + mi][(NLO) + ni], 0, 0, 0);  \
  __builtin_amdgcn_s_setprio(0);

  // ---- prologue: tile0 + next-in-flight set in ledger order h6,h7,h4,h5
  stage(0); stage(1); stage(2); stage(3);
  stage(6); stage(7); stage(4); stage(5);
  asm volatile("s_waitcnt vmcnt(8)" ::: "memory");  // tile0 complete
  memfence_barrier();

  const char* A0b = smem[0][0];
  const char* B0b = smem[0][1];
  const char* A1b = smem[1][0];
  const char* B1b = smem[1][1];

  for (int i = 0; i < NITER; ++i) {
    const int h0 = 8 * i;
    // ===== K-tile 2i (buf0) =====
    // phase 0: A03+B01 reads, MFMA quad (0,0)
    #pragma unroll
    for (int mi = 0; mi < 4; ++mi)
      #pragma unroll
      for (int ks = 0; ks < 2; ++ks) a[mi][ks] = rdA(A0b, mi, ks);
    #pragma unroll
    for (int ni = 0; ni < 2; ++ni)
      #pragma unroll
      for (int ks = 0; ks < 2; ++ks) b[ni][ks] = rdB(B0b, ni, ks);
    memfence_barrier();
    MFMAQ(0, 0);
    memfence_barrier();
    // phase 1: B23 reads, quad (0,2).  (all buf0-B reads retire here)
    #pragma unroll
    for (int ni = 2; ni < 4; ++ni)
      #pragma unroll
      for (int ks = 0; ks < 2; ++ks) b[ni][ks] = rdB(B0b, ni, ks);
    memfence_barrier();
    MFMAQ(0, 2);
    memfence_barrier();
    // phase 2: A47 reads, stage buf0-B for tile 2i+2, quad (4,0)
    #pragma unroll
    for (int mi = 0; mi < 4; ++mi)
      #pragma unroll
      for (int ks = 0; ks < 2; ++ks) a[mi][ks] = rdA(A0b, mi + 4, ks);
    stage(h0 + 10);
    stage(h0 + 11);
    memfence_barrier();
    MFMAQ(4, 0);
    memfence_barrier();
    // phase 3: stage buf0-A for tile 2i+2, quad (4,2), wait tile 2i+1
    stage(h0 + 8);
    stage(h0 + 9);
    memfence_barrier();
    MFMAQ(4, 2);
    asm volatile("s_waitcnt vmcnt(8)" ::: "memory");
    memfence_barrier();

    // ===== K-tile 2i+1 (buf1) =====
    // phase 4
    #pragma unroll
    for (int mi = 0; mi < 4; ++mi)
      #pragma unroll
      for (int ks = 0; ks < 2; ++ks) a[mi][ks] = rdA(A1b, mi, ks);
    #pragma unroll
    for (int ni = 0; ni < 2; ++ni)
      #pragma unroll
      for (int ks = 0; ks < 2; ++ks) b[ni][ks] = rdB(B1b, ni, ks);
    memfence_barrier();
    MFMAQ(0, 0);
    memfence_barrier();
    // phase 5
    #pragma unroll
    for (int ni = 2; ni < 4; ++ni)
      #pragma unroll
      for (int ks = 0; ks < 2; ++ks) b[ni][ks] = rdB(B1b, ni, ks);
    memfence_barrier();
    MFMAQ(0, 2);
    memfence_barrier();
    // phase 6: stage buf1-B for tile 2i+3
    #pragma unroll
    for (int mi = 0; mi < 4; ++mi)
      #pragma unroll
      for (int ks = 0; ks < 2; ++ks) a[mi][ks] = rdA(A1b, mi + 4, ks);
    stage(h0 + 14);
    stage(h0 + 15);
    memfence_barrier();
    MFMAQ(4, 0);
    memfence_barrier();
    // phase 7: stage buf1-A for tile 2i+3, wait tile 2i+2
    stage(h0 + 12);
    stage(h0 + 13);
    memfence_barrier();
    MFMAQ(4, 2);
    asm volatile("s_waitcnt vmcnt(8)" ::: "memory");
    memfence_barrier();
  }
#undef MFMAQ

  // ---- epilogue.  C/D frag: col = l&15, row = (l>>4)*4 + j
  const int row0 = rt * 256 + wr * 128 + (l >> 4) * 4;
  const int col0 = ct * 256 + wc * 64 + (l & 15);
  if (EPI == 0) {
    unsigned short* Oa = (unsigned short*)O0 + (long)mod * sOm;
    #pragma unroll
    for (int m = 0; m < 8; ++m)
      #pragma unroll
      for (int n = 0; n < 4; ++n)
        #pragma unroll
        for (int j = 0; j < 4; ++j) {
          float y = acc[m][n][j];
          float p = __shfl_xor(y, 1);  // partner column (convergent)
          if (!(l & 1)) {
            float glu = fminf(y, 7.f);
            float lin = fminf(fmaxf(p, -7.f), 7.f);
            float sg = 1.f / (1.f + __expf(-1.702f * glu));
            float av = glu * sg * (lin + 1.f);
            Oa[(size_t)(row0 + m * 16 + j) * INTER + ((col0 + n * 16) >> 1)] = f2bf(av);
          }
        }
  } else {
    float* Oz = (float*)O0 + (long)mod * sOm;
    #pragma unroll
    for (int m = 0; m < 8; ++m)
      #pragma unroll
      for (int n = 0; n < 4; ++n)
        #pragma unroll
        for (int j = 0; j < 4; ++j)
          Oz[(size_t)(row0 + m * 16 + j) * H + (col0 + n * 16)] = acc[m][n][j];
  }
}

}  // namespace

extern "C" void kernel_launch(void* const* d_in, const int* in_sizes, int n_in,
                              void* d_out, int out_size, void* d_ws, size_t ws_size,
                              hipStream_t stream) {
  const float* x = (const float*)d_in[0];
  // d_in[1]: modality_mapping (int64) — tokens are pre-grouped in equal halves
  const float* w_norm = (const float*)d_in[2];
  const float* w_up = (const float*)d_in[3];
  const float* w_down = (const float*)d_in[4];

  char* ws = (char*)d_ws;
  unsigned short* wup_bf = (unsigned short*)ws;                  // 134217728 B
  unsigned short* wdn_bf = (unsigned short*)(ws + 134217728L);   //  67108864 B
  unsigned short* tm = (unsigned short*)(ws + 201326592L);       //  33554432 B
  unsigned short* abuf = (unsigned short*)(ws + 234881024L);     // 134217728 B
  // total ws use: 369098752 B

  cvt_f32_bf16<<<2048, 256, 0, stream>>>(w_up, wup_bf, (UP_OUT * M_MOD * H) / 4);
  cvt_f32_bf16<<<2048, 256, 0, stream>>>(w_down, wdn_bf, (H * M_MOD * INTER) / 4);
  rmsnorm_kernel<<<N_TOK, 256, 0, stream>>>(x, w_norm, tm);

  // up: M=4096, N=16384 (64 col tiles/mod), K=2048 -> 2048 blocks
  gemm8p<H, UP_OUT / 256, 0>
      <<<M_MOD * 16 * (UP_OUT / 256), 512, 0, stream>>>(
          tm, wup_bf, abuf, (long)G * H, (long)UP_OUT * H, (long)G * INTER);

  // down: M=4096, N=2048 (8 col tiles/mod), K=8192 -> 256 blocks
  gemm8p<INTER, H / 256, 1>
      <<<M_MOD * 16 * (H / 256), 512, 0, stream>>>(
          abuf, wdn_bf, d_out, (long)G * INTER, (long)H * INTER, (long)G * H);
}

// Round 6
// 876.544 us; speedup vs baseline: 1.1001x; 1.1001x over previous
//
#include <hip/hip_runtime.h>
#include <hip/hip_bf16.h>

#define DEVI __device__ __forceinline__

typedef __bf16 bf16x8 __attribute__((ext_vector_type(8)));
typedef float f32x4 __attribute__((ext_vector_type(4)));

namespace {

constexpr int H = 2048;
constexpr int INTER = 8192;
constexpr int M_MOD = 2;
constexpr int N_TOK = 8192;
constexpr int G = N_TOK / M_MOD;   // 4096 tokens per modality
constexpr int UP_OUT = 2 * INTER;  // 16384

DEVI unsigned short f2bf(float f) {
  unsigned u = __builtin_bit_cast(unsigned, f);
  u += 0x7fffu + ((u >> 16) & 1u);  // round-to-nearest-even
  return (unsigned short)(u >> 16);
}

DEVI void gload_lds16(const void* g, void* lds) {
  __builtin_amdgcn_global_load_lds(
      (const __attribute__((address_space(1))) unsigned int*)g,
      (__attribute__((address_space(3))) unsigned int*)lds, 16, 0, 0);
}

DEVI void memfence_barrier() {
  asm volatile("" ::: "memory");
  __builtin_amdgcn_s_barrier();
  asm volatile("" ::: "memory");
}

__global__ __launch_bounds__(256) void cvt_f32_bf16(
    const float* __restrict__ in, unsigned short* __restrict__ out, int n4) {
  int idx = blockIdx.x * blockDim.x + threadIdx.x;
  int stride = gridDim.x * blockDim.x;
  for (int i = idx; i < n4; i += stride) {
    float4 v = ((const float4*)in)[i];
    ushort4 o;
    o.x = f2bf(v.x); o.y = f2bf(v.y); o.z = f2bf(v.z); o.w = f2bf(v.w);
    ((ushort4*)out)[i] = o;
  }
}

__global__ __launch_bounds__(256) void rmsnorm_kernel(
    const float* __restrict__ x, const float* __restrict__ w_norm,
    unsigned short* __restrict__ tm) {
  const int row = blockIdx.x;
  const int mod = row >> 12;  // 4096 rows per modality
  const int t = threadIdx.x;
  const float4* xr = (const float4*)(x + (size_t)row * H);
  const float4* wr = (const float4*)(w_norm + (size_t)mod * H);

  float4 v0 = xr[t];
  float4 v1 = xr[t + 256];
  float ss = v0.x * v0.x + v0.y * v0.y + v0.z * v0.z + v0.w * v0.w +
             v1.x * v1.x + v1.y * v1.y + v1.z * v1.z + v1.w * v1.w;
  #pragma unroll
  for (int o = 32; o > 0; o >>= 1) ss += __shfl_down(ss, o);
  __shared__ float red[4];
  const int w = t >> 6, l = t & 63;
  if (l == 0) red[w] = ss;
  __syncthreads();
  float tot = red[0] + red[1] + red[2] + red[3];
  float rn = rsqrtf(tot * (1.0f / H) + 1e-6f);

  float4 w0 = wr[t];
  float4 w1 = wr[t + 256];
  ushort4 o0, o1;
  o0.x = f2bf(v0.x * rn * (1.f + w0.x));
  o0.y = f2bf(v0.y * rn * (1.f + w0.y));
  o0.z = f2bf(v0.z * rn * (1.f + w0.z));
  o0.w = f2bf(v0.w * rn * (1.f + w0.w));
  o1.x = f2bf(v1.x * rn * (1.f + w1.x));
  o1.y = f2bf(v1.y * rn * (1.f + w1.y));
  o1.z = f2bf(v1.z * rn * (1.f + w1.z));
  o1.w = f2bf(v1.w * rn * (1.f + w1.w));
  ushort4* tr = (ushort4*)(tm + (size_t)row * H);
  tr[t] = o0;
  tr[t + 256] = o1;
}

// ---------------------------------------------------------------------------
// 256x256-tile 8-phase NT GEMM (T1+T2+T3+T4+T5 stack, m201 schedule).
// C[r,c] = sum_k A[r,k]*B[c,k]; A/B bf16 row-major, K contiguous. BK=64.
// 8 waves (2Mx4N), 512 thr. LDS 128KB: smem[dbuf][A/B][256x64 bf16].
//
// R6 BALANCED DEEP schedule (post-mortem of R5's clustering regression):
//   Quad order (0,0),(0,2),(4,0),(4,2) -> reads 12,4,8,0 per phase; buf-B
//   free after p1, buf-A free after p2. This admits 1 stage/phase with
//   >=2-phase flight (~1250 cyc > ~900 cyc HBM miss latency):
//     p0: h+7   p1: h+5   p2: h+10  p3: h+8  + vmcnt(4)  [tile 2i+1 ready]
//     p4: h+11  p5: h+9   p6: h+14  p7: h+12 + vmcnt(4)  [tile 2i+2 ready]
//   Ledger (2 ops/stage, in-order retire), hand-verified:
//     at p3-end outstanding = [h+6,h+4,h+7,h+5,h+10,h+8]; vmcnt(4) retires
//     {h+6,h+4,h+7,h+5} = tile 2i+1 exactly.  At p7-end outstanding =
//     [h+10,h+8,h+11,h+9,h+14,h+12]; vmcnt(4) retires tile 2i+2 exactly.
//   WAR: every stage >= 1 phase after its region's last read (B last read
//   p1/p5; A last read p2/p6).
//   Prologue: stage {0,1,2,3,6,4}; vmcnt(4) -> tile0 ready, keeps [6,4].
// TAIL: out-of-range stages WRAP (h -= HMAX); HMAX % 8 == 0 so regions and
// ledger identical to steady state; wrapped data never read.
// XOR swizzle: linear gload_lds dest, pre-swizzled global source chunk,
// XOR'd ds_read (verified 0-conflict R2/R4/R5).
// EPI==0: fused swiglu7 -> bf16 (INTER ld). EPI==1: fp32 out (H ld).
// ---------------------------------------------------------------------------
template <int K, int CT_PER_MOD, int EPI>
__global__ __launch_bounds__(512, 2) void gemm8p(
    const unsigned short* __restrict__ A0, const unsigned short* __restrict__ B0,
    void* __restrict__ O0, long sAm, long sBm, long sOm) {
  __shared__ __align__(16) char smem[2][2][32768];

  constexpr int NT = K / 64;     // K-tiles (even for both instantiations)
  constexpr int HMAX = 4 * NT;   // half-tiles total (HMAX % 8 == 0)
  constexpr int NITER = NT / 2;
  constexpr int PER_MOD = 16 * CT_PER_MOD;  // 4096/256 = 16 row tiles
  constexpr int NWG = 2 * PER_MOD;
  constexpr int CPX = NWG / 8;

  // T1: bijective XCD swizzle (NWG % 8 == 0 for both instantiations)
  const int bid0 = blockIdx.x;
  const int bid = (bid0 % 8) * CPX + bid0 / 8;
  const int mod = bid / PER_MOD;
  const int q = bid % PER_MOD;
  const int ct = q / 16;  // col tile; rt inner so consecutive share B-panel
  const int rt = q % 16;

  const unsigned short* A = A0 + (long)mod * sAm;
  const unsigned short* B = B0 + (long)mod * sBm;

  const int t = threadIdx.x;
  const int w = t >> 6;
  const int l = t & 63;
  const int wr = w >> 2;  // 0..1
  const int wc = w & 3;   // 0..3

  const int fr = l & 15;
  const int fk = l >> 4;
  const int frx = (fr & 7) << 4;

  // ---- staging (per thread: 2 x gload_lds per half-tile)
  const unsigned short* gArow = A + (size_t)rt * 256 * K;
  const unsigned short* gBrow = B + (size_t)ct * 256 * K;
  const int srow = t >> 3;                        // 0..63
  const int scol = ((t & 7) ^ (srow & 7)) * 8;    // swizzled chunk (elements)

  // h = 4*tt + qq;  qq: 0=A-half0, 1=A-half1, 2=B-half0, 3=B-half1
  auto stage = [&](int h) {
    if (h >= HMAX) h -= HMAX;  // tail wrap: same regions, exact vmcnt ledger
    const int tt = h >> 2, qq = h & 3;
    const int isB = qq >> 1, half = qq & 1, buf = tt & 1;
    const unsigned short* src = (isB ? gBrow : gArow) +
        (size_t)(half * 128 + srow) * K + tt * 64 + scol;
    char* dst = smem[buf][isB] + half * 16384 + t * 16;
    gload_lds16(src, dst);
    gload_lds16(src + (size_t)64 * K, dst + 8192);
  };

  // ---- LDS fragment reads (swizzled)
  auto rdA = [&](const char* base, int mi, int ks) -> bf16x8 {
    const int row = wr * 128 + mi * 16 + fr;
    return *(const bf16x8*)(base + row * 128 + ((((ks << 2) + fk) << 4) ^ frx));
  };
  auto rdB = [&](const char* base, int ni, int ks) -> bf16x8 {
    const int row = wc * 64 + ni * 16 + fr;
    return *(const bf16x8*)(base + row * 128 + ((((ks << 2) + fk) << 4) ^ frx));
  };

  f32x4 acc[8][4];
  #pragma unroll
  for (int m = 0; m < 8; ++m)
    #pragma unroll
    for (int n = 0; n < 4; ++n) acc[m][n] = (f32x4){0.f, 0.f, 0.f, 0.f};

  bf16x8 a[4][2], b[4][2];

#define MFMAQ(MLO, NLO)                                                       \
  __builtin_amdgcn_s_setprio(1);                                              \
  _Pragma("unroll") for (int ks = 0; ks < 2; ++ks)                            \
  _Pragma("unroll") for (int mi = 0; mi < 4; ++mi)                            \
  _Pragma("unroll") for (int ni = 0; ni < 2; ++ni)                            \
    acc[(MLO) + mi][(NLO) + ni] = __builtin_amdgcn_mfma_f32_16x16x32_bf16(    \
        a[mi][ks], b[(NLO) + ni][ks], acc[(MLO) + mi][(NLO) + ni], 0, 0, 0);  \
  __builtin_amdgcn_s_setprio(0);

  // ---- prologue: tile0 + {h6, h4}; vmcnt(4) -> tile0 ready, keep [6,4]
  stage(0); stage(1); stage(2); stage(3);
  stage(6); stage(4);
  asm volatile("s_waitcnt vmcnt(4)" ::: "memory");
  memfence_barrier();

  const char* A0b = smem[0][0];
  const char* B0b = smem[0][1];
  const char* A1b = smem[1][0];
  const char* B1b = smem[1][1];

  for (int i = 0; i < NITER; ++i) {
    const int h0 = 8 * i;
    // ===== K-tile 2i (buf0) =====
    // phase 0: A03+B01 reads (12), stage h+7 (buf1-B1), MFMA (0,0)
    #pragma unroll
    for (int mi = 0; mi < 4; ++mi)
      #pragma unroll
      for (int ks = 0; ks < 2; ++ks) a[mi][ks] = rdA(A0b, mi, ks);
    #pragma unroll
    for (int ni = 0; ni < 2; ++ni)
      #pragma unroll
      for (int ks = 0; ks < 2; ++ks) b[ni][ks] = rdB(B0b, ni, ks);
    stage(h0 + 7);
    memfence_barrier();
    MFMAQ(0, 0);
    memfence_barrier();
    // phase 1: B23 reads (4), stage h+5 (buf1-A1), MFMA (0,2)
    //          (buf0-B reads all retire here)
    #pragma unroll
    for (int ni = 2; ni < 4; ++ni)
      #pragma unroll
      for (int ks = 0; ks < 2; ++ks) b[ni][ks] = rdB(B0b, ni, ks);
    stage(h0 + 5);
    memfence_barrier();
    MFMAQ(0, 2);
    memfence_barrier();
    // phase 2: A47 reads (8), stage h+10 (buf0-B0, WAR-safe after p1), (4,0)
    #pragma unroll
    for (int mi = 0; mi < 4; ++mi)
      #pragma unroll
      for (int ks = 0; ks < 2; ++ks) a[mi][ks] = rdA(A0b, mi + 4, ks);
    stage(h0 + 10);
    memfence_barrier();
    MFMAQ(4, 0);
    memfence_barrier();
    // phase 3: stage h+8 (buf0-A0, WAR-safe after p2), (4,2), wait tile 2i+1
    stage(h0 + 8);
    memfence_barrier();
    MFMAQ(4, 2);
    asm volatile("s_waitcnt vmcnt(4)" ::: "memory");
    memfence_barrier();

    // ===== K-tile 2i+1 (buf1) =====
    // phase 4: A03+B01 reads, stage h+11 (buf0-B1), MFMA (0,0)
    #pragma unroll
    for (int mi = 0; mi < 4; ++mi)
      #pragma unroll
      for (int ks = 0; ks < 2; ++ks) a[mi][ks] = rdA(A1b, mi, ks);
    #pragma unroll
    for (int ni = 0; ni < 2; ++ni)
      #pragma unroll
      for (int ks = 0; ks < 2; ++ks) b[ni][ks] = rdB(B1b, ni, ks);
    stage(h0 + 11);
    memfence_barrier();
    MFMAQ(0, 0);
    memfence_barrier();
    // phase 5: B23 reads, stage h+9 (buf0-A1), MFMA (0,2)
    #pragma unroll
    for (int ni = 2; ni < 4; ++ni)
      #pragma unroll
      for (int ks = 0; ks < 2; ++ks) b[ni][ks] = rdB(B1b, ni, ks);
    stage(h0 + 9);
    memfence_barrier();
    MFMAQ(0, 2);
    memfence_barrier();
    // phase 6: A47 reads, stage h+14 (buf1-B0, WAR-safe after p5), (4,0)
    #pragma unroll
    for (int mi = 0; mi < 4; ++mi)
      #pragma unroll
      for (int ks = 0; ks < 2; ++ks) a[mi][ks] = rdA(A1b, mi + 4, ks);
    stage(h0 + 14);
    memfence_barrier();
    MFMAQ(4, 0);
    memfence_barrier();
    // phase 7: stage h+12 (buf1-A0, WAR-safe after p6), (4,2), wait tile 2i+2
    stage(h0 + 12);
    memfence_barrier();
    MFMAQ(4, 2);
    asm volatile("s_waitcnt vmcnt(4)" ::: "memory");
    memfence_barrier();
  }
#undef MFMAQ

  // ---- epilogue.  C/D frag: col = l&15, row = (l>>4)*4 + j
  const int row0 = rt * 256 + wr * 128 + (l >> 4) * 4;
  const int col0 = ct * 256 + wc * 64 + (l & 15);
  if (EPI == 0) {
    unsigned short* Oa = (unsigned short*)O0 + (long)mod * sOm;
    #pragma unroll
    for (int m = 0; m < 8; ++m)
      #pragma unroll
      for (int n = 0; n < 4; ++n)
        #pragma unroll
        for (int j = 0; j < 4; ++j) {
          float y = acc[m][n][j];
          float p = __shfl_xor(y, 1);  // partner column (convergent)
          if (!(l & 1)) {
            float glu = fminf(y, 7.f);
            float lin = fminf(fmaxf(p, -7.f), 7.f);
            float sg = 1.f / (1.f + __expf(-1.702f * glu));
            float av = glu * sg * (lin + 1.f);
            Oa[(size_t)(row0 + m * 16 + j) * INTER + ((col0 + n * 16) >> 1)] = f2bf(av);
          }
        }
  } else {
    float* Oz = (float*)O0 + (long)mod * sOm;
    #pragma unroll
    for (int m = 0; m < 8; ++m)
      #pragma unroll
      for (int n = 0; n < 4; ++n)
        #pragma unroll
        for (int j = 0; j < 4; ++j)
          Oz[(size_t)(row0 + m * 16 + j) * H + (col0 + n * 16)] = acc[m][n][j];
  }
}

}  // namespace

extern "C" void kernel_launch(void* const* d_in, const int* in_sizes, int n_in,
                              void* d_out, int out_size, void* d_ws, size_t ws_size,
                              hipStream_t stream) {
  const float* x = (const float*)d_in[0];
  // d_in[1]: modality_mapping (int64) — tokens are pre-grouped in equal halves
  const float* w_norm = (const float*)d_in[2];
  const float* w_up = (const float*)d_in[3];
  const float* w_down = (const float*)d_in[4];

  char* ws = (char*)d_ws;
  unsigned short* wup_bf = (unsigned short*)ws;                  // 134217728 B
  unsigned short* wdn_bf = (unsigned short*)(ws + 134217728L);   //  67108864 B
  unsigned short* tm = (unsigned short*)(ws + 201326592L);       //  33554432 B
  unsigned short* abuf = (unsigned short*)(ws + 234881024L);     // 134217728 B
  // total ws use: 369098752 B

  cvt_f32_bf16<<<2048, 256, 0, stream>>>(w_up, wup_bf, (UP_OUT * M_MOD * H) / 4);
  cvt_f32_bf16<<<2048, 256, 0, stream>>>(w_down, wdn_bf, (H * M_MOD * INTER) / 4);
  rmsnorm_kernel<<<N_TOK, 256, 0, stream>>>(x, w_norm, tm);

  // up: M=4096, N=16384 (64 col tiles/mod), K=2048 -> 2048 blocks
  gemm8p<H, UP_OUT / 256, 0>
      <<<M_MOD * 16 * (UP_OUT / 256), 512, 0, stream>>>(
          tm, wup_bf, abuf, (long)G * H, (long)UP_OUT * H, (long)G * INTER);

  // down: M=4096, N=2048 (8 col tiles/mod), K=8192 -> 256 blocks
  gemm8p<INTER, H / 256, 1>
      <<<M_MOD * 16 * (H / 256), 512, 0, stream>>>(
          abuf, wdn_bf, d_out, (long)G * INTER, (long)H * INTER, (long)G * H);
}